// Round 4
// baseline (358.560 us; speedup 1.0000x reference)
//
#include <hip/hip_runtime.h>
#include <hip/hip_bf16.h>

#define DATA_DIM 59
#define IN_DIM   64
#define NSTEPS   4          // midpoint RK2 x 4 steps = 8 f-evals
#define ROWS_PER_BLOCK 128  // 4 waves x 32 batch-cols
#define LDS_STRIDE 68       // pad: 16B-aligned float4 rows, spreads banks

typedef __attribute__((ext_vector_type(8)))  short    short8;
typedef __attribute__((ext_vector_type(16))) float    f32x16;

// f32 -> bf16 bits (RNE) via HIP intrinsic; compiler fuses pairs into v_cvt_pk_bf16_f32
__device__ __forceinline__ unsigned short bfbits(float f) {
  __hip_bfloat16 h = __float2bfloat16(f);
  unsigned short u;
  __builtin_memcpy(&u, &h, sizeof(u));
  return u;
}

// pack two f32 -> bf16x2 in one dword (lo in low 16)
__device__ __forceinline__ unsigned pkbf(float a, float b) {
  return (unsigned)bfbits(a) | ((unsigned)bfbits(b) << 16);
}

__device__ __forceinline__ short8 frag4(unsigned w0, unsigned w1, unsigned w2, unsigned w3) {
  union { unsigned u[4]; short8 s; } cv;
  cv.u[0] = w0; cv.u[1] = w1; cv.u[2] = w2; cv.u[3] = w3;
  return cv.s;
}

__device__ __forceinline__ f32x16 mfma16(short8 a, short8 b, f32x16 c) {
  return __builtin_amdgcn_mfma_f32_32x32x16_bf16(a, b, c, 0, 0, 0);
}

// D-layout tile (16 f32 regs, feats (reg&3)+8*(reg>>2)+4*hf [+32*tile]) ->
// two B-operand k-chunks (16 feats each) via cvt_pk + permlane32_swap.
// swap(a,b): ret0[l<32]=a, ret0[l>=32]=b[l-32]; ret1[l<32]=a[l+32], ret1[l>=32]=b.
__device__ __forceinline__ void tile_to_frags(const f32x16 d, short8& fa, short8& fb) {
  unsigned p01 = pkbf(d[0], d[1]);
  unsigned p23 = pkbf(d[2], d[3]);
  unsigned p45 = pkbf(d[4], d[5]);
  unsigned p67 = pkbf(d[6], d[7]);
  auto sA = __builtin_amdgcn_permlane32_swap(p01, p45, false, false);
  auto sB = __builtin_amdgcn_permlane32_swap(p23, p67, false, false);
  fa = frag4(sA[0], sB[0], sA[1], sB[1]);
  unsigned q01 = pkbf(d[8],  d[9]);
  unsigned q23 = pkbf(d[10], d[11]);
  unsigned q45 = pkbf(d[12], d[13]);
  unsigned q67 = pkbf(d[14], d[15]);
  auto tA = __builtin_amdgcn_permlane32_swap(q01, q45, false, false);
  auto tB = __builtin_amdgcn_permlane32_swap(q23, q67, false, false);
  fb = frag4(tA[0], tB[0], tA[1], tB[1]);
}

// One MLP evaluation: f = W3*relu(W2*relu(W1*z + b1) + b2) + b3
// input Z given as 4 B-frags (k-chunks of 16 feats x 32 cols); output in D-layout.
__device__ __forceinline__ void feval(const short8 wf[3][2][4],
                                      const unsigned wbw[3][2], const short8 onesf,
                                      short8 c0, short8 c1, short8 c2, short8 c3,
                                      f32x16& o0, f32x16& o1)
{
  #pragma unroll
  for (int l = 0; l < 3; ++l) {
    f32x16 t0 = {}, t1 = {};
    t0 = mfma16(wf[l][0][0], c0, t0);  t1 = mfma16(wf[l][1][0], c0, t1);
    t0 = mfma16(wf[l][0][1], c1, t0);  t1 = mfma16(wf[l][1][1], c1, t1);
    t0 = mfma16(wf[l][0][2], c2, t0);  t1 = mfma16(wf[l][1][2], c2, t1);
    t0 = mfma16(wf[l][0][3], c3, t0);  t1 = mfma16(wf[l][1][3], c3, t1);
    // bias as extra K-chunk: A has bias in k=0 column, B is ones at k=0
    t0 = mfma16(frag4(wbw[l][0], 0u, 0u, 0u), onesf, t0);
    t1 = mfma16(frag4(wbw[l][1], 0u, 0u, 0u), onesf, t1);
    if (l < 2) {
      #pragma unroll
      for (int r = 0; r < 16; ++r) { t0[r] = fmaxf(t0[r], 0.f); t1[r] = fmaxf(t1[r], 0.f); }
      tile_to_frags(t0, c0, c1);
      tile_to_frags(t1, c2, c3);
    } else {
      o0 = t0; o1 = t1;
    }
  }
}

__global__ __launch_bounds__(256, 2)
void node_rk2(const float* __restrict__ x,
              const float* __restrict__ W1, const float* __restrict__ b1,
              const float* __restrict__ W2, const float* __restrict__ b2,
              const float* __restrict__ W3, const float* __restrict__ b3,
              float* __restrict__ out)
{
  __shared__ float lds[ROWS_PER_BLOCK * LDS_STRIDE];
  const int tid  = threadIdx.x;
  const int lane = tid & 63;
  const int wid  = tid >> 6;
  const int hf   = lane >> 5;   // wave half (k-group / feature subgroup)
  const int ln   = lane & 31;   // batch col within wave / weight row

  const long long base = (long long)blockIdx.x * ROWS_PER_BLOCK;

  // ---- stage x into LDS (coalesced), zero-fill the 5 augmented dims ----
  for (int r = tid; r < ROWS_PER_BLOCK; r += 256) {
    #pragma unroll
    for (int c = DATA_DIM; c < IN_DIM; ++c) lds[r * LDS_STRIDE + c] = 0.f;
  }
  const float* xb = x + base * DATA_DIM;
  for (int i = tid; i < ROWS_PER_BLOCK * DATA_DIM; i += 256) {
    int r = i / DATA_DIM;
    int c = i - r * DATA_DIM;
    lds[r * LDS_STRIDE + c] = xb[i];
  }

  // ---- build weight A-fragments in registers (bf16) ----
  // A frag for (layer l, row-tile t, k-chunk c): lane holds
  // W[ln+32t][16c + 8*hf + j], j=0..7
  const float* Wp[3] = { W1, W2, W3 };
  const float* bp[3] = { b1, b2, b3 };
  short8   wf[3][2][4];
  unsigned wbw[3][2];
  #pragma unroll
  for (int l = 0; l < 3; ++l) {
    #pragma unroll
    for (int t = 0; t < 2; ++t) {
      const int row = ln + 32 * t;
      #pragma unroll
      for (int c = 0; c < 4; ++c) {
        const float* s = Wp[l] + row * 64 + c * 16 + hf * 8;
        short8 f;
        #pragma unroll
        for (int j = 0; j < 8; ++j) f[j] = (short)bfbits(s[j]);
        wf[l][t][c] = f;
      }
      wbw[l][t] = (hf == 0) ? (unsigned)bfbits(bp[l][row]) : 0u;
    }
  }
  const short8 onesf = frag4((hf == 0) ? 0x00003F80u : 0u, 0u, 0u, 0u); // B[k=0][*]=1

  __syncthreads();

  // ---- load h (fp32 state) into D-layout registers ----
  const int col = wid * 32 + ln;
  f32x16 h0, h1;
  #pragma unroll
  for (int r = 0; r < 16; ++r) {
    const int feat = (r & 3) + 8 * (r >> 2) + 4 * hf;
    h0[r] = lds[col * LDS_STRIDE + feat];
    h1[r] = lds[col * LDS_STRIDE + feat + 32];
  }

  // ---- midpoint RK2, all in registers (no LDS, no barriers) ----
  const float dt = 1.0f / (float)NSTEPS;
  short8 c0, c1, c2, c3;
  f32x16 k0, k1;
  #pragma unroll 1
  for (int s = 0; s < NSTEPS; ++s) {
    tile_to_frags(h0, c0, c1);
    tile_to_frags(h1, c2, c3);
    feval(wf, wbw, onesf, c0, c1, c2, c3, k0, k1);   // k1 = f(h)
    f32x16 y0, y1;
    #pragma unroll
    for (int r = 0; r < 16; ++r) {
      y0[r] = fmaf(0.5f * dt, k0[r], h0[r]);
      y1[r] = fmaf(0.5f * dt, k1[r], h1[r]);
    }
    tile_to_frags(y0, c0, c1);
    tile_to_frags(y1, c2, c3);
    feval(wf, wbw, onesf, c0, c1, c2, c3, k0, k1);   // k2 = f(h + dt/2 k1)
    #pragma unroll
    for (int r = 0; r < 16; ++r) {
      h0[r] = fmaf(dt, k0[r], h0[r]);
      h1[r] = fmaf(dt, k1[r], h1[r]);
    }
  }

  // ---- transpose back through LDS, coalesced float4 store ----
  __syncthreads();   // all waves are past their h-load reads
  #pragma unroll
  for (int r = 0; r < 16; ++r) {
    const int feat = (r & 3) + 8 * (r >> 2) + 4 * hf;
    lds[col * LDS_STRIDE + feat]      = h0[r];
    lds[col * LDS_STRIDE + feat + 32] = h1[r];
  }
  __syncthreads();
  float* ob = out + base * 64;
  for (int i = tid; i < ROWS_PER_BLOCK * IN_DIM / 4; i += 256) {
    const int r = i >> 4;
    const int c = (i & 15) << 2;
    float4 v = *reinterpret_cast<const float4*>(&lds[r * LDS_STRIDE + c]);
    reinterpret_cast<float4*>(ob)[i] = v;
  }
}

extern "C" void kernel_launch(void* const* d_in, const int* in_sizes, int n_in,
                              void* d_out, int out_size, void* d_ws, size_t ws_size,
                              hipStream_t stream) {
  const float* x  = (const float*)d_in[0];
  const float* W1 = (const float*)d_in[1];
  const float* b1 = (const float*)d_in[2];
  const float* W2 = (const float*)d_in[3];
  const float* b2 = (const float*)d_in[4];
  const float* W3 = (const float*)d_in[5];
  const float* b3 = (const float*)d_in[6];
  float* out = (float*)d_out;

  const int batch   = in_sizes[0] / DATA_DIM;      // 524288
  const int nblocks = batch / ROWS_PER_BLOCK;      // 4096
  hipLaunchKernelGGL(node_rk2, dim3(nblocks), dim3(256), 0, stream,
                     x, W1, b1, W2, b2, W3, b3, out);
}